// Round 1
// 881.458 us; speedup vs baseline: 1.1057x; 1.1057x over previous
//
// Round 3: fused scores+softmax+PV attention kernel (eliminates pack_vT, the ctx
// GEMM, and the 33.5MB/layer bf16 attn round-trip); XOR-swizzled LDS for K/P/V^T
// fragment reads (kills the 16-way bank conflict on ds_read_b128).
#include <hip/hip_runtime.h>
#include <hip/hip_bf16.h>

#define B_ 8
#define L_ 512
#define D_ 512
#define H_ 8
#define F_ 2048
#define NL_ 4
#define BL 4096            // B_*L_
#define EPS_ 1e-5f

typedef __bf16 bf16_t;
typedef bf16_t bf16x8 __attribute__((ext_vector_type(8)));
typedef float f32x4 __attribute__((ext_vector_type(4)));
typedef unsigned short u16x4 __attribute__((ext_vector_type(4)));

__device__ __forceinline__ unsigned short f2b_rn(float f) {
  unsigned u = __builtin_bit_cast(unsigned, f);
  u = (u + 0x7fffu + ((u >> 16) & 1u)) >> 16;
  return (unsigned short)u;
}

// async global->LDS, 16B per lane. LDS dest must be wave-uniform base + lane*16.
__device__ __forceinline__ void gload_lds16(const unsigned short* g, unsigned short* l) {
  __builtin_amdgcn_global_load_lds(
      (const __attribute__((address_space(1))) void*)g,
      (__attribute__((address_space(3))) void*)l, 16, 0, 0);
}

// C[M,N] = relu?(scale * A[M,K] @ B[N,K]^T + bias[N]); optional fp32 and bf16 outputs.
// Batched via blockIdx.z with (z/zi, z%zi) stride decomposition for A/B/C.
template<int BM, int BN, int MT, int NT>
__global__ __launch_bounds__(256)
void gemm_bt(const unsigned short* __restrict__ A, int lda, long sAo, long sAi,
             const unsigned short* __restrict__ Bm, int ldb, long sBo, long sBi,
             float* __restrict__ Cf, unsigned short* __restrict__ Cb, int ldc,
             long sCo, long sCi,
             const float* __restrict__ bias, int K, float scale, int relu, int zi)
{
  static_assert(BM == MT * 32 && BN == NT * 32, "waves are 2x2");
  __shared__ unsigned short As[BM * 32];
  __shared__ unsigned short Bs[BN * 32];
  const int tid  = threadIdx.x;
  const int lane = tid & 63;
  const int wave = tid >> 6;
  const int wm = (wave >> 1) * (MT * 16);
  const int wn = (wave & 1) * (NT * 16);
  const int m0 = blockIdx.x * BM;
  const int n0 = blockIdx.y * BN;
  const int z  = blockIdx.z;
  const long offA = (long)(z / zi) * sAo + (long)(z % zi) * sAi;
  const long offB = (long)(z / zi) * sBo + (long)(z % zi) * sBi;
  const long offC = (long)(z / zi) * sCo + (long)(z % zi) * sCi;

  f32x4 acc[MT][NT] = {};

  for (int k0 = 0; k0 < K; k0 += 32) {
    __syncthreads();
#pragma unroll
    for (int j = 0; j < BM / 64; ++j) {
      int c = tid + j * 256;
      int r = c >> 2, cc = (c & 3) * 8;
      gload_lds16(A + offA + (long)(m0 + r) * lda + (k0 + cc), &As[c * 8]);
    }
#pragma unroll
    for (int j = 0; j < BN / 64; ++j) {
      int c = tid + j * 256;
      int r = c >> 2, cc = (c & 3) * 8;
      gload_lds16(Bm + offB + (long)(n0 + r) * ldb + (k0 + cc), &Bs[c * 8]);
    }
    __syncthreads();
    bf16x8 af[MT], bfr[NT];
#pragma unroll
    for (int mt = 0; mt < MT; ++mt)
      af[mt] = *(const bf16x8*)(&As[(wm + mt * 16 + (lane & 15)) * 32 + (lane >> 4) * 8]);
#pragma unroll
    for (int nt = 0; nt < NT; ++nt)
      bfr[nt] = *(const bf16x8*)(&Bs[(wn + nt * 16 + (lane & 15)) * 32 + (lane >> 4) * 8]);
#pragma unroll
    for (int mt = 0; mt < MT; ++mt)
#pragma unroll
      for (int nt = 0; nt < NT; ++nt)
        acc[mt][nt] = __builtin_amdgcn_mfma_f32_16x16x32_bf16(af[mt], bfr[nt], acc[mt][nt], 0, 0, 0);
  }

  // C/D layout: col=lane&15, row=(lane>>4)*4+r
#pragma unroll
  for (int nt = 0; nt < NT; ++nt) {
    const int col = n0 + wn + nt * 16 + (lane & 15);
    const float bb = bias ? bias[col] : 0.f;
#pragma unroll
    for (int mt = 0; mt < MT; ++mt) {
#pragma unroll
      for (int r = 0; r < 4; ++r) {
        const int row = m0 + wm + mt * 16 + (lane >> 4) * 4 + r;
        float v = acc[mt][nt][r] * scale + bb;
        if (relu) v = fmaxf(v, 0.f);
        const long o = offC + (long)row * ldc + col;
        if (Cf) Cf[o] = v;
        if (Cb) Cb[o] = f2b_rn(v);
      }
    }
  }
}

// Fused attention: per (64-row q-block, z=(b*8+h)):
//   QK^T (MFMA, swizzled K tile) -> row softmax in regs -> write fp32 attn out
//   -> P (bf16, swizzled) into the K LDS buffer, V^T (from reg prefetch) into a
//   swizzled LDS buffer -> PV MFMA -> ctx bf16 [4096,512] direct.
__global__ __launch_bounds__(256)
void attn_fused(const unsigned short* __restrict__ qkv,
                float* __restrict__ attnf,
                unsigned short* __restrict__ ctxb) {
  __shared__ __align__(16) unsigned short Qs[64 * 64];    // 8 KB, linear
  __shared__ __align__(16) unsigned short KP[512 * 64];   // 64 KB: K [512s][64d] (src-preswizzled), then P [64q][512s] (swizzled)
  __shared__ __align__(16) unsigned short VT[64 * 512];   // 64 KB: V^T [64d][512s] (swizzled)
  const int tid = threadIdx.x, lane = tid & 63, wave = tid >> 6;
  const int lo4 = lane & 15, hi4 = lane >> 4;
  const int q0 = blockIdx.x * 64;
  const int z = blockIdx.y, b = z >> 3, h = z & 7;
  const unsigned short* qbase = qkv + (long)b * 512 * 1536 + h * 64;
  const unsigned short* kbase = qbase + 512;
  const unsigned short* vbase = qbase + 1024;

  // V prefetch into regs: 16 x 16B per thread (drained by barrier-1 vmcnt(0)).
  // unit j: d8 = j>>1 (8-elem d group), s = (j&1)*256 + tid
  bf16x8 vreg[16];
#pragma unroll
  for (int j = 0; j < 16; ++j) {
    const int d8 = j >> 1;
    const int s = (j & 1) * 256 + tid;
    vreg[j] = *(const bf16x8*)(vbase + (long)s * 1536 + d8 * 8);
  }

  // stage Q [64,64] linear
#pragma unroll
  for (int j = 0; j < 2; ++j) {
    int c = tid + j * 256;
    int r = c >> 3, cc = (c & 7) * 8;
    gload_lds16(qbase + (long)(q0 + r) * 1536 + cc, &Qs[c * 8]);
  }
  // stage K [512,64] with pre-swizzled SOURCE (rule #21: linear LDS dest,
  // inverse-swizzled source, swizzled read): chunk' = chunk ^ (row&7)
#pragma unroll
  for (int j = 0; j < 16; ++j) {
    int c = tid + j * 256;
    int r = c >> 3, ch = (c & 7) ^ (r & 7);
    gload_lds16(kbase + (long)r * 1536 + ch * 8, &KP[c * 8]);
  }
  __syncthreads();

  const bf16x8 af0 = *(const bf16x8*)&Qs[(wave * 16 + lo4) * 64 + hi4 * 8];
  const bf16x8 af1 = *(const bf16x8*)&Qs[(wave * 16 + lo4) * 64 + 32 + hi4 * 8];

  f32x4 acc[32];
#pragma unroll
  for (int st = 0; st < 32; ++st) {
    const int n = st * 16 + lo4;
    const int sw = n & 7;
    f32x4 a = {};
    const bf16x8 b0 = *(const bf16x8*)&KP[n * 64 + ((hi4 ^ sw) * 8)];
    const bf16x8 b1 = *(const bf16x8*)&KP[n * 64 + (((hi4 + 4) ^ sw) * 8)];
    a = __builtin_amdgcn_mfma_f32_16x16x32_bf16(af0, b0, a, 0, 0, 0);
    a = __builtin_amdgcn_mfma_f32_16x16x32_bf16(af1, b1, a, 0, 0, 0);
    acc[st] = a;
  }

  // scale + row softmax. Row r's 512 values live in 16 lanes (lo4) x 32 st.
  float mx[4] = {-1e30f, -1e30f, -1e30f, -1e30f};
#pragma unroll
  for (int st = 0; st < 32; ++st)
#pragma unroll
    for (int r = 0; r < 4; ++r) {
      acc[st][r] *= 0.125f;
      mx[r] = fmaxf(mx[r], acc[st][r]);
    }
#pragma unroll
  for (int msk = 1; msk < 16; msk <<= 1)
#pragma unroll
    for (int r = 0; r < 4; ++r) mx[r] = fmaxf(mx[r], __shfl_xor(mx[r], msk));
  float sm[4] = {0.f, 0.f, 0.f, 0.f};
#pragma unroll
  for (int st = 0; st < 32; ++st)
#pragma unroll
    for (int r = 0; r < 4; ++r) {
      const float e = __expf(acc[st][r] - mx[r]);
      acc[st][r] = e;
      sm[r] += e;
    }
#pragma unroll
  for (int msk = 1; msk < 16; msk <<= 1)
#pragma unroll
    for (int r = 0; r < 4; ++r) sm[r] += __shfl_xor(sm[r], msk);
  float inv[4];
#pragma unroll
  for (int r = 0; r < 4; ++r) inv[r] = 1.f / sm[r];

  __syncthreads();   // all waves done reading K tile; KP becomes the P buffer

  // V^T into LDS, swizzled (element idx ^ ((d&7)<<3), 16B-chunk granularity).
  // Writes are conflict-free: per (j,jj) lanes hold consecutive s at uniform d.
#pragma unroll
  for (int j = 0; j < 16; ++j) {
    const int d8 = j >> 1;
    const int s = (j & 1) * 256 + tid;
#pragma unroll
    for (int jj = 0; jj < 8; ++jj) {
      const int d = d8 * 8 + jj;
      VT[(d * 512 + s) ^ ((d & 7) << 3)] = ((const unsigned short*)&vreg[j])[jj];
    }
  }

  // fp32 attn output (required) + bf16 P into KP (swizzled rows of 512)
  const long obase = (long)z * 262144 + (long)(q0 + wave * 16 + hi4 * 4) * 512 + lo4;
  const int qloc = wave * 16 + hi4 * 4;
#pragma unroll
  for (int st = 0; st < 32; ++st)
#pragma unroll
    for (int r = 0; r < 4; ++r) {
      const float v = acc[st][r] * inv[r];
      attnf[obase + (long)r * 512 + st * 16] = v;
      const int q = qloc + r;
      const int s = st * 16 + lo4;
      KP[(q * 512 + s) ^ ((q & 7) << 3)] = f2b_rn(v);
    }
  __syncthreads();

  // PV: each wave computes a 32q x 32d sub-tile of the 64x64 ctx block.
  const int wm = (wave >> 1) * 32, wn = (wave & 1) * 32;
  f32x4 acc2[2][2] = {};
#pragma unroll
  for (int k0 = 0; k0 < 512; k0 += 32) {
    bf16x8 pa[2], vb[2];
#pragma unroll
    for (int mt = 0; mt < 2; ++mt) {
      const int m = wm + mt * 16 + lo4;
      pa[mt] = *(const bf16x8*)&KP[(m * 512 + k0 + hi4 * 8) ^ ((m & 7) << 3)];
    }
#pragma unroll
    for (int nt = 0; nt < 2; ++nt) {
      const int n = wn + nt * 16 + lo4;
      vb[nt] = *(const bf16x8*)&VT[(n * 512 + k0 + hi4 * 8) ^ ((n & 7) << 3)];
    }
#pragma unroll
    for (int mt = 0; mt < 2; ++mt)
#pragma unroll
      for (int nt = 0; nt < 2; ++nt)
        acc2[mt][nt] = __builtin_amdgcn_mfma_f32_16x16x32_bf16(pa[mt], vb[nt], acc2[mt][nt], 0, 0, 0);
  }

  // ctx bf16 write: row = b*512 + q, col = h*64 + d
#pragma unroll
  for (int nt = 0; nt < 2; ++nt) {
    const int d = wn + nt * 16 + lo4;
#pragma unroll
    for (int mt = 0; mt < 2; ++mt)
#pragma unroll
      for (int r = 0; r < 4; ++r) {
        const int q = q0 + wm + mt * 16 + hi4 * 4 + r;
        ctxb[((long)(b * 512 + q)) * 512 + h * 64 + d] = f2b_rn(acc2[mt][nt][r]);
      }
  }
}

// out = LayerNorm(a + b) * g + be ; fp32 + bf16, float4-vectorized, 128 threads.
__global__ __launch_bounds__(128)
void resid_ln(const float* __restrict__ a, const float* __restrict__ b,
              const float* __restrict__ g, const float* __restrict__ be,
              float* __restrict__ outf, unsigned short* __restrict__ outb) {
  const long row = blockIdx.x;
  const int t = threadIdx.x;
  const int wave = t >> 6, lane = t & 63;
  const f32x4 va = *(const f32x4*)&a[row * 512 + t * 4];
  const f32x4 vb = *(const f32x4*)&b[row * 512 + t * 4];
  f32x4 v;
  float s = 0.f, s2 = 0.f;
#pragma unroll
  for (int i = 0; i < 4; ++i) { v[i] = va[i] + vb[i]; s += v[i]; s2 += v[i] * v[i]; }
  for (int o = 32; o > 0; o >>= 1) { s += __shfl_down(s, o); s2 += __shfl_down(s2, o); }
  __shared__ float red[4];
  if (lane == 0) { red[wave] = s; red[2 + wave] = s2; }
  __syncthreads();
  s = red[0] + red[1];
  s2 = red[2] + red[3];
  const float mu  = s * (1.f / 512.f);
  const float var = s2 * (1.f / 512.f) - mu * mu;
  const float ri = rsqrtf(var + EPS_);
  const f32x4 vg = *(const f32x4*)&g[t * 4];
  const f32x4 ve = *(const f32x4*)&be[t * 4];
  f32x4 y;
  u16x4 yb;
#pragma unroll
  for (int i = 0; i < 4; ++i) { y[i] = (v[i] - mu) * ri * vg[i] + ve[i]; yb[i] = f2b_rn(y[i]); }
  *(f32x4*)&outf[row * 512 + t * 4] = y;
  *(u16x4*)&outb[row * 512 + t * 4] = yb;
}

__global__ void f2b_arr(const float* __restrict__ in, unsigned short* __restrict__ out, long n4) {
  long i = (long)blockIdx.x * 256 + threadIdx.x;
  const long stride = (long)gridDim.x * 256;
  for (; i < n4; i += stride) {
    const f32x4 v = *(const f32x4*)&in[i * 4];
    u16x4 o;
#pragma unroll
    for (int k = 0; k < 4; ++k) o[k] = f2b_rn(v[k]);
    *(u16x4*)&out[i * 4] = o;
  }
}

__global__ void copy_conv(const float* __restrict__ in, float* __restrict__ outf,
                          unsigned short* __restrict__ outb, long n4) {
  long i = (long)blockIdx.x * 256 + threadIdx.x;
  const long stride = (long)gridDim.x * 256;
  for (; i < n4; i += stride) {
    const f32x4 v = *(const f32x4*)&in[i * 4];
    u16x4 o;
#pragma unroll
    for (int k = 0; k < 4; ++k) o[k] = f2b_rn(v[k]);
    *(f32x4*)&outf[i * 4] = v;
    *(u16x4*)&outb[i * 4] = o;
  }
}

extern "C" void kernel_launch(void* const* d_in, const int* in_sizes, int n_in,
                              void* d_out, int out_size, void* d_ws, size_t ws_size,
                              hipStream_t stream) {
  const float* src  = (const float*)d_in[0];
  const float* Wqkv = (const float*)d_in[1];
  const float* bqkv = (const float*)d_in[2];
  const float* Wo   = (const float*)d_in[3];
  const float* bo   = (const float*)d_in[4];
  const float* W1   = (const float*)d_in[5];
  const float* b1   = (const float*)d_in[6];
  const float* W2   = (const float*)d_in[7];
  const float* b2   = (const float*)d_in[8];
  const float* g1   = (const float*)d_in[9];
  const float* be1  = (const float*)d_in[10];
  const float* g2   = (const float*)d_in[11];
  const float* be2  = (const float*)d_in[12];

  char* p = (char*)d_ws;
  auto take = [&](size_t bytes) { void* r = (void*)p; p += (bytes + 255) & ~(size_t)255; return r; };
  float* x        = (float*)take((size_t)BL * 512 * 4);
  float* x1       = (float*)take((size_t)BL * 512 * 4);
  float* attn_out = (float*)take((size_t)BL * 512 * 4);
  float* ff2      = (float*)take((size_t)BL * 512 * 4);
  unsigned short* xbf    = (unsigned short*)take((size_t)BL * 512 * 2);
  unsigned short* qkvbf  = (unsigned short*)take((size_t)BL * 1536 * 2);
  unsigned short* ctxbf  = (unsigned short*)take((size_t)BL * 512 * 2);
  unsigned short* ff1bf  = (unsigned short*)take((size_t)BL * 2048 * 2);
  unsigned short* Wqkvb  = (unsigned short*)take((size_t)4 * 1536 * 512 * 2);
  unsigned short* Wob    = (unsigned short*)take((size_t)4 * 512 * 512 * 2);
  unsigned short* W1b    = (unsigned short*)take((size_t)4 * 2048 * 512 * 2);
  unsigned short* W2b    = (unsigned short*)take((size_t)4 * 512 * 2048 * 2);

  f2b_arr<<<1024, 256, 0, stream>>>(Wqkv, Wqkvb, 4L * 1536 * 512 / 4);
  f2b_arr<<<512,  256, 0, stream>>>(Wo,   Wob,   4L * 512 * 512 / 4);
  f2b_arr<<<1024, 256, 0, stream>>>(W1,   W1b,   4L * 2048 * 512 / 4);
  f2b_arr<<<1024, 256, 0, stream>>>(W2,   W2b,   4L * 512 * 2048 / 4);
  copy_conv<<<1024, 256, 0, stream>>>(src, x, xbf, (long)BL * 512 / 4);

  float* out_x    = (float*)d_out;
  float* out_attn = out_x + (size_t)BL * 512;

  for (int i = 0; i < NL_; ++i) {
    // QKV: [4096,1536] = x @ Wqkv^T + bqkv   (bf16 out)
    gemm_bt<128, 128, 4, 4><<<dim3(BL / 128, 1536 / 128, 1), 256, 0, stream>>>(
        xbf, 512, 0, 0, Wqkvb + (size_t)i * 1536 * 512, 512, 0, 0,
        nullptr, qkvbf, 1536, 0, 0, bqkv + (size_t)i * 1536, 512, 1.f, 0, 1);

    // fused scores+softmax+PV: fp32 attn -> d_out, ctx bf16 -> ctxbf
    float* attnL = out_attn + (size_t)i * 64 * 512 * 512;
    attn_fused<<<dim3(8, 64), 256, 0, stream>>>(qkvbf, attnL, ctxbf);

    // attn_out = ctx @ Wo^T + bo  (fp32)
    gemm_bt<128, 64, 4, 2><<<dim3(32, 8, 1), 256, 0, stream>>>(
        ctxbf, 512, 0, 0, Wob + (size_t)i * 512 * 512, 512, 0, 0,
        attn_out, nullptr, 512, 0, 0, bo + (size_t)i * 512, 512, 1.f, 0, 1);

    // x1 = LN(x + attn_out)
    resid_ln<<<BL, 128, 0, stream>>>(x, attn_out, g1 + (size_t)i * 512, be1 + (size_t)i * 512, x1, xbf);

    // ff1 = relu(x1 @ W1^T + b1)  (bf16)
    gemm_bt<128, 128, 4, 4><<<dim3(32, 16, 1), 256, 0, stream>>>(
        xbf, 512, 0, 0, W1b + (size_t)i * 2048 * 512, 512, 0, 0,
        nullptr, ff1bf, 2048, 0, 0, b1 + (size_t)i * 2048, 512, 1.f, 1, 1);

    // ff2 = ff1 @ W2^T + b2  (fp32)
    gemm_bt<128, 64, 4, 2><<<dim3(32, 8, 1), 256, 0, stream>>>(
        ff1bf, 2048, 0, 0, W2b + (size_t)i * 512 * 2048, 2048, 0, 0,
        ff2, nullptr, 512, 0, 0, b2 + (size_t)i * 512, 2048, 1.f, 0, 1);

    // x = LN(x1 + ff2); final layer writes straight to d_out
    resid_ln<<<BL, 128, 0, stream>>>(x1, ff2, g2 + (size_t)i * 512, be2 + (size_t)i * 512,
                                     (i == 3) ? out_x : x, xbf);
  }
}

// Round 2
// 842.902 us; speedup vs baseline: 1.1562x; 1.0457x over previous
//
// Round 4: swapped-operand attention (mfma(K,Q) / mfma(V^T,P)) -> coalesced f32x4
// nontemporal attn stores, b64 P writes, 4-shfl softmax; XCD-aware block swizzle
// for all GEMMs (per-XCD L2-resident A panels) + attn (K/V group locality);
// QKV retiled 64x128 -> 768 blocks (3/CU balanced).
#include <hip/hip_runtime.h>
#include <hip/hip_bf16.h>

#define B_ 8
#define L_ 512
#define D_ 512
#define H_ 8
#define F_ 2048
#define NL_ 4
#define BL 4096            // B_*L_
#define EPS_ 1e-5f

typedef __bf16 bf16_t;
typedef bf16_t bf16x8 __attribute__((ext_vector_type(8)));
typedef float f32x4 __attribute__((ext_vector_type(4)));
typedef unsigned short u16x4 __attribute__((ext_vector_type(4)));

__device__ __forceinline__ unsigned short f2b_rn(float f) {
  unsigned u = __builtin_bit_cast(unsigned, f);
  u = (u + 0x7fffu + ((u >> 16) & 1u)) >> 16;
  return (unsigned short)u;
}

// async global->LDS, 16B per lane. LDS dest must be wave-uniform base + lane*16.
__device__ __forceinline__ void gload_lds16(const unsigned short* g, unsigned short* l) {
  __builtin_amdgcn_global_load_lds(
      (const __attribute__((address_space(1))) void*)g,
      (__attribute__((address_space(3))) void*)l, 16, 0, 0);
}

// C[M,N] = relu?(scale * A[M,K] @ B[N,K]^T + bias[N]); optional fp32 and bf16 outputs.
// Batched via blockIdx.z with (z/zi, z%zi) stride decomposition for A/B/C.
// XCD-aware swizzle (z==1, gridX%8==0): each XCD owns a contiguous M-chunk so the
// A panel stays resident in its private L2 across the N sweep.
template<int BM, int BN, int MT, int NT>
__global__ __launch_bounds__(256)
void gemm_bt(const unsigned short* __restrict__ A, int lda, long sAo, long sAi,
             const unsigned short* __restrict__ Bm, int ldb, long sBo, long sBi,
             float* __restrict__ Cf, unsigned short* __restrict__ Cb, int ldc,
             long sCo, long sCi,
             const float* __restrict__ bias, int K, float scale, int relu, int zi)
{
  static_assert(BM == MT * 32 && BN == NT * 32, "waves are 2x2");
  __shared__ unsigned short As[BM * 32];
  __shared__ unsigned short Bs[BN * 32];
  const int tid  = threadIdx.x;
  const int lane = tid & 63;
  const int wave = tid >> 6;
  const int wm = (wave >> 1) * (MT * 16);
  const int wn = (wave & 1) * (NT * 16);
  int bx = blockIdx.x, by = blockIdx.y;
  if (gridDim.z == 1 && (gridDim.x & 7) == 0) {
    const int gx = gridDim.x, cx = gx >> 3;
    const int lid = by * gx + bx;
    const int xcd = lid & 7;
    const int t = lid >> 3;
    bx = xcd * cx + (t % cx);
    by = t / cx;
  }
  const int m0 = bx * BM;
  const int n0 = by * BN;
  const int z  = blockIdx.z;
  const long offA = (long)(z / zi) * sAo + (long)(z % zi) * sAi;
  const long offB = (long)(z / zi) * sBo + (long)(z % zi) * sBi;
  const long offC = (long)(z / zi) * sCo + (long)(z % zi) * sCi;

  f32x4 acc[MT][NT] = {};

  for (int k0 = 0; k0 < K; k0 += 32) {
    __syncthreads();
#pragma unroll
    for (int j = 0; j < BM / 64; ++j) {
      int c = tid + j * 256;
      int r = c >> 2, cc = (c & 3) * 8;
      gload_lds16(A + offA + (long)(m0 + r) * lda + (k0 + cc), &As[c * 8]);
    }
#pragma unroll
    for (int j = 0; j < BN / 64; ++j) {
      int c = tid + j * 256;
      int r = c >> 2, cc = (c & 3) * 8;
      gload_lds16(Bm + offB + (long)(n0 + r) * ldb + (k0 + cc), &Bs[c * 8]);
    }
    __syncthreads();
    bf16x8 af[MT], bfr[NT];
#pragma unroll
    for (int mt = 0; mt < MT; ++mt)
      af[mt] = *(const bf16x8*)(&As[(wm + mt * 16 + (lane & 15)) * 32 + (lane >> 4) * 8]);
#pragma unroll
    for (int nt = 0; nt < NT; ++nt)
      bfr[nt] = *(const bf16x8*)(&Bs[(wn + nt * 16 + (lane & 15)) * 32 + (lane >> 4) * 8]);
#pragma unroll
    for (int mt = 0; mt < MT; ++mt)
#pragma unroll
      for (int nt = 0; nt < NT; ++nt)
        acc[mt][nt] = __builtin_amdgcn_mfma_f32_16x16x32_bf16(af[mt], bfr[nt], acc[mt][nt], 0, 0, 0);
  }

  // C/D layout: col=lane&15, row=(lane>>4)*4+r
#pragma unroll
  for (int nt = 0; nt < NT; ++nt) {
    const int col = n0 + wn + nt * 16 + (lane & 15);
    const float bb = bias ? bias[col] : 0.f;
#pragma unroll
    for (int mt = 0; mt < MT; ++mt) {
#pragma unroll
      for (int r = 0; r < 4; ++r) {
        const int row = m0 + wm + mt * 16 + (lane >> 4) * 4 + r;
        float v = acc[mt][nt][r] * scale + bb;
        if (relu) v = fmaxf(v, 0.f);
        const long o = offC + (long)row * ldc + col;
        if (Cf) Cf[o] = v;
        if (Cb) Cb[o] = f2b_rn(v);
      }
    }
  }
}

// Fused attention, swapped operands. Per (64-row q-block, z=(b*8+h)):
//   scores^T = mfma(K,Q) so each lane owns ONE q-row (col=q, row=s) ->
//   scalar softmax + 2-lane-pair shfl reduce -> coalesced f32x4 nontemporal
//   attn stores + b64 P writes into LDS -> ctx^T = mfma(V^T,P) -> u16x4 ctx.
__global__ __launch_bounds__(256)
void attn_fused(const unsigned short* __restrict__ qkv,
                float* __restrict__ attnf,
                unsigned short* __restrict__ ctxb) {
  __shared__ __align__(16) unsigned short Qs[64 * 64];    // 8 KB, linear
  __shared__ __align__(16) unsigned short KP[512 * 64];   // 64 KB: K (src-preswizzled) then P (swizzled)
  __shared__ __align__(16) unsigned short VT[64 * 512];   // 64 KB: V^T (swizzled)
  const int tid = threadIdx.x, lane = tid & 63, wave = tid >> 6;
  const int lo4 = lane & 15, hi4 = lane >> 4;
  // XCD remap: each XCD owns 8 consecutive (b,h) groups -> K/V L2-resident.
  int bxr = blockIdx.x, byr = blockIdx.y;
  {
    const int lid = byr * 8 + bxr;           // grid is (8, 64)
    const int xcd = lid & 7;
    const int t = lid >> 3;                  // [0,64)
    byr = xcd * 8 + (t & 7);
    bxr = t >> 3;
  }
  const int q0 = bxr * 64;
  const int z = byr, b = z >> 3, h = z & 7;
  const unsigned short* qbase = qkv + (long)b * 512 * 1536 + h * 64;
  const unsigned short* kbase = qbase + 512;
  const unsigned short* vbase = qbase + 1024;

  // V prefetch into regs: 16 x 16B per thread (drained by barrier-1 vmcnt(0)).
  bf16x8 vreg[16];
#pragma unroll
  for (int j = 0; j < 16; ++j) {
    const int d8 = j >> 1;
    const int s = (j & 1) * 256 + tid;
    vreg[j] = *(const bf16x8*)(vbase + (long)s * 1536 + d8 * 8);
  }

  // stage Q [64,64] linear
#pragma unroll
  for (int j = 0; j < 2; ++j) {
    int c = tid + j * 256;
    int r = c >> 3, cc = (c & 7) * 8;
    gload_lds16(qbase + (long)(q0 + r) * 1536 + cc, &Qs[c * 8]);
  }
  // stage K [512,64] with pre-swizzled SOURCE (linear LDS dest + swizzled read)
#pragma unroll
  for (int j = 0; j < 16; ++j) {
    int c = tid + j * 256;
    int r = c >> 3, ch = (c & 7) ^ (r & 7);
    gload_lds16(kbase + (long)r * 1536 + ch * 8, &KP[c * 8]);
  }
  __syncthreads();

  // Q fragments (B operand): row n = q = wave*16 + lo4
  const bf16x8 qf0 = *(const bf16x8*)&Qs[(wave * 16 + lo4) * 64 + hi4 * 8];
  const bf16x8 qf1 = *(const bf16x8*)&Qs[(wave * 16 + lo4) * 64 + 32 + hi4 * 8];

  // scores^T: acc[st] holds col=q (this lane's row), row = s = st*16 + hi4*4 + r
  f32x4 acc[32];
#pragma unroll
  for (int st = 0; st < 32; ++st) {
    const int n = st * 16 + lo4;
    const int sw = lo4 & 7;
    f32x4 a = {};
    const bf16x8 k0f = *(const bf16x8*)&KP[n * 64 + ((hi4 ^ sw) * 8)];
    const bf16x8 k1f = *(const bf16x8*)&KP[n * 64 + (((hi4 + 4) ^ sw) * 8)];
    a = __builtin_amdgcn_mfma_f32_16x16x32_bf16(k0f, qf0, a, 0, 0, 0);
    a = __builtin_amdgcn_mfma_f32_16x16x32_bf16(k1f, qf1, a, 0, 0, 0);
    acc[st] = a;
  }

  // scalar row softmax: this lane's q-row is spread over hi4 groups (shfl 16,32)
  float mx = -1e30f;
#pragma unroll
  for (int st = 0; st < 32; ++st)
#pragma unroll
    for (int r = 0; r < 4; ++r) {
      acc[st][r] *= 0.125f;
      mx = fmaxf(mx, acc[st][r]);
    }
  mx = fmaxf(mx, __shfl_xor(mx, 16));
  mx = fmaxf(mx, __shfl_xor(mx, 32));
  float sm = 0.f;
#pragma unroll
  for (int st = 0; st < 32; ++st)
#pragma unroll
    for (int r = 0; r < 4; ++r) {
      const float e = __expf(acc[st][r] - mx);
      acc[st][r] = e;
      sm += e;
    }
  sm += __shfl_xor(sm, 16);
  sm += __shfl_xor(sm, 32);
  const float inv = 1.f / sm;

  __syncthreads();   // all waves done reading K tile; KP becomes the P buffer

  // V^T into LDS, swizzled (element idx ^ ((d&7)<<3)).
#pragma unroll
  for (int j = 0; j < 16; ++j) {
    const int d8 = j >> 1;
    const int s = (j & 1) * 256 + tid;
#pragma unroll
    for (int jj = 0; jj < 8; ++jj) {
      const int d = d8 * 8 + jj;
      VT[(d * 512 + s) ^ ((d & 7) << 3)] = ((const unsigned short*)&vreg[j])[jj];
    }
  }

  // fp32 attn out: 4 consecutive s per lane -> f32x4 nontemporal; P -> b64 LDS.
  const int q = wave * 16 + lo4;
  float* aout = attnf + (long)z * 262144 + (long)(q0 + q) * 512;
#pragma unroll
  for (int st = 0; st < 32; ++st) {
    f32x4 pv;
    u16x4 pb;
#pragma unroll
    for (int r = 0; r < 4; ++r) {
      pv[r] = acc[st][r] * inv;
      pb[r] = f2b_rn(pv[r]);
    }
    __builtin_nontemporal_store(pv, (f32x4*)(aout + st * 16 + hi4 * 4));
    *(u16x4*)&KP[(q * 512 + st * 16 + hi4 * 4) ^ ((q & 7) << 3)] = pb;
  }
  __syncthreads();

  // PV swapped: A = V^T (rows d), B = P (rows q) -> col=q, row=d.
  const int wq = (wave >> 1) * 32, wd = (wave & 1) * 32;
  f32x4 acc2[2][2] = {};
#pragma unroll
  for (int k0 = 0; k0 < 512; k0 += 32) {
    bf16x8 vf[2], pf[2];
#pragma unroll
    for (int mt = 0; mt < 2; ++mt) {
      const int d = wd + mt * 16 + lo4;
      vf[mt] = *(const bf16x8*)&VT[(d * 512 + k0 + hi4 * 8) ^ ((d & 7) << 3)];
    }
#pragma unroll
    for (int nt = 0; nt < 2; ++nt) {
      const int m = wq + nt * 16 + lo4;
      pf[nt] = *(const bf16x8*)&KP[(m * 512 + k0 + hi4 * 8) ^ ((m & 7) << 3)];
    }
#pragma unroll
    for (int mt = 0; mt < 2; ++mt)
#pragma unroll
      for (int nt = 0; nt < 2; ++nt)
        acc2[mt][nt] = __builtin_amdgcn_mfma_f32_16x16x32_bf16(vf[mt], pf[nt], acc2[mt][nt], 0, 0, 0);
  }

  // ctx write: col=q (lo4), row=d (hi4*4+r) -> u16x4 along d.
#pragma unroll
  for (int nt = 0; nt < 2; ++nt) {
    const int qq = q0 + wq + nt * 16 + lo4;
    unsigned short* cb = ctxb + ((long)(b * 512 + qq)) * 512 + h * 64;
#pragma unroll
    for (int mt = 0; mt < 2; ++mt) {
      u16x4 o;
#pragma unroll
      for (int r = 0; r < 4; ++r) o[r] = f2b_rn(acc2[mt][nt][r]);
      *(u16x4*)&cb[wd + mt * 16 + hi4 * 4] = o;
    }
  }
}

// out = LayerNorm(a + b) * g + be ; fp32 + bf16, float4-vectorized, 128 threads.
__global__ __launch_bounds__(128)
void resid_ln(const float* __restrict__ a, const float* __restrict__ b,
              const float* __restrict__ g, const float* __restrict__ be,
              float* __restrict__ outf, unsigned short* __restrict__ outb) {
  const long row = blockIdx.x;
  const int t = threadIdx.x;
  const int wave = t >> 6, lane = t & 63;
  const f32x4 va = *(const f32x4*)&a[row * 512 + t * 4];
  const f32x4 vb = *(const f32x4*)&b[row * 512 + t * 4];
  f32x4 v;
  float s = 0.f, s2 = 0.f;
#pragma unroll
  for (int i = 0; i < 4; ++i) { v[i] = va[i] + vb[i]; s += v[i]; s2 += v[i] * v[i]; }
  for (int o = 32; o > 0; o >>= 1) { s += __shfl_down(s, o); s2 += __shfl_down(s2, o); }
  __shared__ float red[4];
  if (lane == 0) { red[wave] = s; red[2 + wave] = s2; }
  __syncthreads();
  s = red[0] + red[1];
  s2 = red[2] + red[3];
  const float mu  = s * (1.f / 512.f);
  const float var = s2 * (1.f / 512.f) - mu * mu;
  const float ri = rsqrtf(var + EPS_);
  const f32x4 vg = *(const f32x4*)&g[t * 4];
  const f32x4 ve = *(const f32x4*)&be[t * 4];
  f32x4 y;
  u16x4 yb;
#pragma unroll
  for (int i = 0; i < 4; ++i) { y[i] = (v[i] - mu) * ri * vg[i] + ve[i]; yb[i] = f2b_rn(y[i]); }
  *(f32x4*)&outf[row * 512 + t * 4] = y;
  *(u16x4*)&outb[row * 512 + t * 4] = yb;
}

__global__ void f2b_arr(const float* __restrict__ in, unsigned short* __restrict__ out, long n4) {
  long i = (long)blockIdx.x * 256 + threadIdx.x;
  const long stride = (long)gridDim.x * 256;
  for (; i < n4; i += stride) {
    const f32x4 v = *(const f32x4*)&in[i * 4];
    u16x4 o;
#pragma unroll
    for (int k = 0; k < 4; ++k) o[k] = f2b_rn(v[k]);
    *(u16x4*)&out[i * 4] = o;
  }
}

__global__ void copy_conv(const float* __restrict__ in, float* __restrict__ outf,
                          unsigned short* __restrict__ outb, long n4) {
  long i = (long)blockIdx.x * 256 + threadIdx.x;
  const long stride = (long)gridDim.x * 256;
  for (; i < n4; i += stride) {
    const f32x4 v = *(const f32x4*)&in[i * 4];
    u16x4 o;
#pragma unroll
    for (int k = 0; k < 4; ++k) o[k] = f2b_rn(v[k]);
    *(f32x4*)&outf[i * 4] = v;
    *(u16x4*)&outb[i * 4] = o;
  }
}

extern "C" void kernel_launch(void* const* d_in, const int* in_sizes, int n_in,
                              void* d_out, int out_size, void* d_ws, size_t ws_size,
                              hipStream_t stream) {
  const float* src  = (const float*)d_in[0];
  const float* Wqkv = (const float*)d_in[1];
  const float* bqkv = (const float*)d_in[2];
  const float* Wo   = (const float*)d_in[3];
  const float* bo   = (const float*)d_in[4];
  const float* W1   = (const float*)d_in[5];
  const float* b1   = (const float*)d_in[6];
  const float* W2   = (const float*)d_in[7];
  const float* b2   = (const float*)d_in[8];
  const float* g1   = (const float*)d_in[9];
  const float* be1  = (const float*)d_in[10];
  const float* g2   = (const float*)d_in[11];
  const float* be2  = (const float*)d_in[12];

  char* p = (char*)d_ws;
  auto take = [&](size_t bytes) { void* r = (void*)p; p += (bytes + 255) & ~(size_t)255; return r; };
  float* x        = (float*)take((size_t)BL * 512 * 4);
  float* x1       = (float*)take((size_t)BL * 512 * 4);
  float* attn_out = (float*)take((size_t)BL * 512 * 4);
  float* ff2      = (float*)take((size_t)BL * 512 * 4);
  unsigned short* xbf    = (unsigned short*)take((size_t)BL * 512 * 2);
  unsigned short* qkvbf  = (unsigned short*)take((size_t)BL * 1536 * 2);
  unsigned short* ctxbf  = (unsigned short*)take((size_t)BL * 512 * 2);
  unsigned short* ff1bf  = (unsigned short*)take((size_t)BL * 2048 * 2);
  unsigned short* Wqkvb  = (unsigned short*)take((size_t)4 * 1536 * 512 * 2);
  unsigned short* Wob    = (unsigned short*)take((size_t)4 * 512 * 512 * 2);
  unsigned short* W1b    = (unsigned short*)take((size_t)4 * 2048 * 512 * 2);
  unsigned short* W2b    = (unsigned short*)take((size_t)4 * 512 * 2048 * 2);

  f2b_arr<<<1024, 256, 0, stream>>>(Wqkv, Wqkvb, 4L * 1536 * 512 / 4);
  f2b_arr<<<512,  256, 0, stream>>>(Wo,   Wob,   4L * 512 * 512 / 4);
  f2b_arr<<<1024, 256, 0, stream>>>(W1,   W1b,   4L * 2048 * 512 / 4);
  f2b_arr<<<1024, 256, 0, stream>>>(W2,   W2b,   4L * 512 * 2048 / 4);
  copy_conv<<<1024, 256, 0, stream>>>(src, x, xbf, (long)BL * 512 / 4);

  float* out_x    = (float*)d_out;
  float* out_attn = out_x + (size_t)BL * 512;

  for (int i = 0; i < NL_; ++i) {
    // QKV: [4096,1536] = x @ Wqkv^T + bqkv  (bf16 out); 64x128 tiles -> 768 blocks
    gemm_bt<64, 128, 2, 4><<<dim3(BL / 64, 1536 / 128, 1), 256, 0, stream>>>(
        xbf, 512, 0, 0, Wqkvb + (size_t)i * 1536 * 512, 512, 0, 0,
        nullptr, qkvbf, 1536, 0, 0, bqkv + (size_t)i * 1536, 512, 1.f, 0, 1);

    // fused scores+softmax+PV: fp32 attn -> d_out, ctx bf16 -> ctxbf
    float* attnL = out_attn + (size_t)i * 64 * 512 * 512;
    attn_fused<<<dim3(8, 64), 256, 0, stream>>>(qkvbf, attnL, ctxbf);

    // attn_out = ctx @ Wo^T + bo  (fp32)
    gemm_bt<128, 64, 4, 2><<<dim3(32, 8, 1), 256, 0, stream>>>(
        ctxbf, 512, 0, 0, Wob + (size_t)i * 512 * 512, 512, 0, 0,
        attn_out, nullptr, 512, 0, 0, bo + (size_t)i * 512, 512, 1.f, 0, 1);

    // x1 = LN(x + attn_out)
    resid_ln<<<BL, 128, 0, stream>>>(x, attn_out, g1 + (size_t)i * 512, be1 + (size_t)i * 512, x1, xbf);

    // ff1 = relu(x1 @ W1^T + b1)  (bf16)
    gemm_bt<128, 128, 4, 4><<<dim3(32, 16, 1), 256, 0, stream>>>(
        xbf, 512, 0, 0, W1b + (size_t)i * 2048 * 512, 512, 0, 0,
        nullptr, ff1bf, 2048, 0, 0, b1 + (size_t)i * 2048, 512, 1.f, 1, 1);

    // ff2 = ff1 @ W2^T + b2  (fp32)
    gemm_bt<128, 64, 4, 2><<<dim3(32, 8, 1), 256, 0, stream>>>(
        ff1bf, 2048, 0, 0, W2b + (size_t)i * 512 * 2048, 2048, 0, 0,
        ff2, nullptr, 512, 0, 0, b2 + (size_t)i * 512, 2048, 1.f, 0, 1);

    // x = LN(x1 + ff2); final layer writes straight to d_out
    resid_ln<<<BL, 128, 0, stream>>>(x1, ff2, g2 + (size_t)i * 512, be2 + (size_t)i * 512,
                                     (i == 3) ? out_x : x, xbf);
  }
}

// Round 3
// 797.931 us; speedup vs baseline: 1.2214x; 1.0564x over previous
//
// Round 5: 2-phase prefetch double-buffered GEMM (issue next tile's global_load_lds
// before current tile's MFMA; ONE barrier per K-step -> load latency hides under
// compute); attn: fp32 attention stores moved AFTER the pre-PV barrier so the
// barrier's vmcnt(0) no longer waits for 128KB of HBM stores per block.
#include <hip/hip_runtime.h>
#include <hip/hip_bf16.h>

#define B_ 8
#define L_ 512
#define D_ 512
#define H_ 8
#define F_ 2048
#define NL_ 4
#define BL 4096            // B_*L_
#define EPS_ 1e-5f

typedef __bf16 bf16_t;
typedef bf16_t bf16x8 __attribute__((ext_vector_type(8)));
typedef float f32x4 __attribute__((ext_vector_type(4)));
typedef unsigned short u16x4 __attribute__((ext_vector_type(4)));

__device__ __forceinline__ unsigned short f2b_rn(float f) {
  unsigned u = __builtin_bit_cast(unsigned, f);
  u = (u + 0x7fffu + ((u >> 16) & 1u)) >> 16;
  return (unsigned short)u;
}

// async global->LDS, 16B per lane. LDS dest must be wave-uniform base + lane*16.
__device__ __forceinline__ void gload_lds16(const unsigned short* g, unsigned short* l) {
  __builtin_amdgcn_global_load_lds(
      (const __attribute__((address_space(1))) void*)g,
      (__attribute__((address_space(3))) void*)l, 16, 0, 0);
}

// C[M,N] = relu?(scale * A[M,K] @ B[N,K]^T + bias[N]); optional fp32 and bf16 outputs.
// Batched via blockIdx.z with (z/zi, z%zi) stride decomposition for A/B/C.
// XCD-aware swizzle (z==1, gridX%8==0): each XCD owns a contiguous M-chunk.
// 2-phase pipeline: double-buffered LDS, next tile staged before current compute,
// single __syncthreads per K-step (its vmcnt(0) drains loads that overlapped MFMA).
template<int BM, int BN, int MT, int NT>
__global__ __launch_bounds__(256)
void gemm_bt(const unsigned short* __restrict__ A, int lda, long sAo, long sAi,
             const unsigned short* __restrict__ Bm, int ldb, long sBo, long sBi,
             float* __restrict__ Cf, unsigned short* __restrict__ Cb, int ldc,
             long sCo, long sCi,
             const float* __restrict__ bias, int K, float scale, int relu, int zi)
{
  static_assert(BM == MT * 32 && BN == NT * 32, "waves are 2x2");
  __shared__ unsigned short As[2][BM * 32];
  __shared__ unsigned short Bs[2][BN * 32];
  const int tid  = threadIdx.x;
  const int lane = tid & 63;
  const int wave = tid >> 6;
  const int wm = (wave >> 1) * (MT * 16);
  const int wn = (wave & 1) * (NT * 16);
  int bx = blockIdx.x, by = blockIdx.y;
  if (gridDim.z == 1 && (gridDim.x & 7) == 0) {
    const int gx = gridDim.x, cx = gx >> 3;
    const int lid = by * gx + bx;
    const int xcd = lid & 7;
    const int t = lid >> 3;
    bx = xcd * cx + (t % cx);
    by = t / cx;
  }
  const int m0 = bx * BM;
  const int n0 = by * BN;
  const int z  = blockIdx.z;
  const long offA = (long)(z / zi) * sAo + (long)(z % zi) * sAi;
  const long offB = (long)(z / zi) * sBo + (long)(z % zi) * sBi;
  const long offC = (long)(z / zi) * sCo + (long)(z % zi) * sCi;

  const unsigned short* Ab = A + offA + (long)m0 * lda;
  const unsigned short* Bb = Bm + offB + (long)n0 * ldb;

  auto stage = [&](int buf, int k0) {
#pragma unroll
    for (int j = 0; j < BM / 64; ++j) {
      int c = tid + j * 256;
      int r = c >> 2, cc = (c & 3) * 8;
      gload_lds16(Ab + (long)r * lda + (k0 + cc), &As[buf][c * 8]);
    }
#pragma unroll
    for (int j = 0; j < BN / 64; ++j) {
      int c = tid + j * 256;
      int r = c >> 2, cc = (c & 3) * 8;
      gload_lds16(Bb + (long)r * ldb + (k0 + cc), &Bs[buf][c * 8]);
    }
  };

  f32x4 acc[MT][NT] = {};

  stage(0, 0);
  __syncthreads();
  int cur = 0;
  for (int k0 = 0; k0 < K; k0 += 32) {
    if (k0 + 32 < K) stage(cur ^ 1, k0 + 32);   // prefetch next tile (async)
    bf16x8 af[MT], bfr[NT];
#pragma unroll
    for (int mt = 0; mt < MT; ++mt)
      af[mt] = *(const bf16x8*)(&As[cur][(wm + mt * 16 + (lane & 15)) * 32 + (lane >> 4) * 8]);
#pragma unroll
    for (int nt = 0; nt < NT; ++nt)
      bfr[nt] = *(const bf16x8*)(&Bs[cur][(wn + nt * 16 + (lane & 15)) * 32 + (lane >> 4) * 8]);
#pragma unroll
    for (int mt = 0; mt < MT; ++mt)
#pragma unroll
      for (int nt = 0; nt < NT; ++nt)
        acc[mt][nt] = __builtin_amdgcn_mfma_f32_16x16x32_bf16(af[mt], bfr[nt], acc[mt][nt], 0, 0, 0);
    __syncthreads();   // drains prefetch (overlapped with MFMA) + guards buffer swap
    cur ^= 1;
  }

  // C/D layout: col=lane&15, row=(lane>>4)*4+r
#pragma unroll
  for (int nt = 0; nt < NT; ++nt) {
    const int col = n0 + wn + nt * 16 + (lane & 15);
    const float bb = bias ? bias[col] : 0.f;
#pragma unroll
    for (int mt = 0; mt < MT; ++mt) {
#pragma unroll
      for (int r = 0; r < 4; ++r) {
        const int row = m0 + wm + mt * 16 + (lane >> 4) * 4 + r;
        float v = acc[mt][nt][r] * scale + bb;
        if (relu) v = fmaxf(v, 0.f);
        const long o = offC + (long)row * ldc + col;
        if (Cf) Cf[o] = v;
        if (Cb) Cb[o] = f2b_rn(v);
      }
    }
  }
}

// Fused attention, swapped operands. Per (64-row q-block, z=(b*8+h)):
//   scores^T = mfma(K,Q) -> scalar softmax (lane owns one q-row) -> P (bf16) into
//   LDS + V^T into LDS -> barrier -> coalesced f32x4 nontemporal attn stores
//   (AFTER the barrier: drain overlaps PV) -> ctx^T = mfma(V^T,P) -> u16x4 ctx.
__global__ __launch_bounds__(256)
void attn_fused(const unsigned short* __restrict__ qkv,
                float* __restrict__ attnf,
                unsigned short* __restrict__ ctxb) {
  __shared__ __align__(16) unsigned short Qs[64 * 64];    // 8 KB, linear
  __shared__ __align__(16) unsigned short KP[512 * 64];   // 64 KB: K (src-preswizzled) then P (swizzled)
  __shared__ __align__(16) unsigned short VT[64 * 512];   // 64 KB: V^T (swizzled)
  const int tid = threadIdx.x, lane = tid & 63, wave = tid >> 6;
  const int lo4 = lane & 15, hi4 = lane >> 4;
  // XCD remap: each XCD owns 8 consecutive (b,h) groups -> K/V L2-resident.
  int bxr = blockIdx.x, byr = blockIdx.y;
  {
    const int lid = byr * 8 + bxr;           // grid is (8, 64)
    const int xcd = lid & 7;
    const int t = lid >> 3;                  // [0,64)
    byr = xcd * 8 + (t & 7);
    bxr = t >> 3;
  }
  const int q0 = bxr * 64;
  const int z = byr, b = z >> 3, h = z & 7;
  const unsigned short* qbase = qkv + (long)b * 512 * 1536 + h * 64;
  const unsigned short* kbase = qbase + 512;
  const unsigned short* vbase = qbase + 1024;

  // V prefetch into regs: 16 x 16B per thread (drained by barrier-1 vmcnt(0)).
  bf16x8 vreg[16];
#pragma unroll
  for (int j = 0; j < 16; ++j) {
    const int d8 = j >> 1;
    const int s = (j & 1) * 256 + tid;
    vreg[j] = *(const bf16x8*)(vbase + (long)s * 1536 + d8 * 8);
  }

  // stage Q [64,64] linear
#pragma unroll
  for (int j = 0; j < 2; ++j) {
    int c = tid + j * 256;
    int r = c >> 3, cc = (c & 7) * 8;
    gload_lds16(qbase + (long)(q0 + r) * 1536 + cc, &Qs[c * 8]);
  }
  // stage K [512,64] with pre-swizzled SOURCE (linear LDS dest + swizzled read)
#pragma unroll
  for (int j = 0; j < 16; ++j) {
    int c = tid + j * 256;
    int r = c >> 3, ch = (c & 7) ^ (r & 7);
    gload_lds16(kbase + (long)r * 1536 + ch * 8, &KP[c * 8]);
  }
  __syncthreads();

  // Q fragments (B operand): row n = q = wave*16 + lo4
  const bf16x8 qf0 = *(const bf16x8*)&Qs[(wave * 16 + lo4) * 64 + hi4 * 8];
  const bf16x8 qf1 = *(const bf16x8*)&Qs[(wave * 16 + lo4) * 64 + 32 + hi4 * 8];

  // scores^T: acc[st] holds col=q (this lane's row), row = s = st*16 + hi4*4 + r
  f32x4 acc[32];
#pragma unroll
  for (int st = 0; st < 32; ++st) {
    const int n = st * 16 + lo4;
    const int sw = lo4 & 7;
    f32x4 a = {};
    const bf16x8 k0f = *(const bf16x8*)&KP[n * 64 + ((hi4 ^ sw) * 8)];
    const bf16x8 k1f = *(const bf16x8*)&KP[n * 64 + (((hi4 + 4) ^ sw) * 8)];
    a = __builtin_amdgcn_mfma_f32_16x16x32_bf16(k0f, qf0, a, 0, 0, 0);
    a = __builtin_amdgcn_mfma_f32_16x16x32_bf16(k1f, qf1, a, 0, 0, 0);
    acc[st] = a;
  }

  // scalar row softmax: this lane's q-row is spread over hi4 groups (shfl 16,32)
  float mx = -1e30f;
#pragma unroll
  for (int st = 0; st < 32; ++st)
#pragma unroll
    for (int r = 0; r < 4; ++r) {
      acc[st][r] *= 0.125f;
      mx = fmaxf(mx, acc[st][r]);
    }
  mx = fmaxf(mx, __shfl_xor(mx, 16));
  mx = fmaxf(mx, __shfl_xor(mx, 32));
  float sm = 0.f;
#pragma unroll
  for (int st = 0; st < 32; ++st)
#pragma unroll
    for (int r = 0; r < 4; ++r) {
      const float e = __expf(acc[st][r] - mx);
      acc[st][r] = e;
      sm += e;
    }
  sm += __shfl_xor(sm, 16);
  sm += __shfl_xor(sm, 32);
  const float inv = 1.f / sm;

  __syncthreads();   // all waves done reading K tile; KP becomes the P buffer

  // V^T into LDS, swizzled (element idx ^ ((d&7)<<3)).
#pragma unroll
  for (int j = 0; j < 16; ++j) {
    const int d8 = j >> 1;
    const int s = (j & 1) * 256 + tid;
#pragma unroll
    for (int jj = 0; jj < 8; ++jj) {
      const int d = d8 * 8 + jj;
      VT[(d * 512 + s) ^ ((d & 7) << 3)] = ((const unsigned short*)&vreg[j])[jj];
    }
  }

  // normalize P in regs; bf16 P -> LDS (b64). Global stores deferred past barrier.
  const int q = wave * 16 + lo4;
#pragma unroll
  for (int st = 0; st < 32; ++st) {
    u16x4 pb;
#pragma unroll
    for (int r = 0; r < 4; ++r) {
      acc[st][r] *= inv;
      pb[r] = f2b_rn(acc[st][r]);
    }
    *(u16x4*)&KP[(q * 512 + st * 16 + hi4 * 4) ^ ((q & 7) << 3)] = pb;
  }
  __syncthreads();   // lgkm drain only matters; no outstanding global stores here

  // fp32 attn out now: stores drain under PV + next block's work, nothing waits.
  float* aout = attnf + (long)z * 262144 + (long)(q0 + q) * 512;
#pragma unroll
  for (int st = 0; st < 32; ++st)
    __builtin_nontemporal_store(acc[st], (f32x4*)(aout + st * 16 + hi4 * 4));

  // PV swapped: A = V^T (rows d), B = P (rows q) -> col=q, row=d.
  const int wq = (wave >> 1) * 32, wd = (wave & 1) * 32;
  f32x4 acc2[2][2] = {};
#pragma unroll
  for (int k0 = 0; k0 < 512; k0 += 32) {
    bf16x8 vf[2], pf[2];
#pragma unroll
    for (int mt = 0; mt < 2; ++mt) {
      const int d = wd + mt * 16 + lo4;
      vf[mt] = *(const bf16x8*)&VT[(d * 512 + k0 + hi4 * 8) ^ ((d & 7) << 3)];
    }
#pragma unroll
    for (int nt = 0; nt < 2; ++nt) {
      const int m = wq + nt * 16 + lo4;
      pf[nt] = *(const bf16x8*)&KP[(m * 512 + k0 + hi4 * 8) ^ ((m & 7) << 3)];
    }
#pragma unroll
    for (int mt = 0; mt < 2; ++mt)
#pragma unroll
      for (int nt = 0; nt < 2; ++nt)
        acc2[mt][nt] = __builtin_amdgcn_mfma_f32_16x16x32_bf16(vf[mt], pf[nt], acc2[mt][nt], 0, 0, 0);
  }

  // ctx write: col=q (lo4), row=d (hi4*4+r) -> u16x4 along d.
#pragma unroll
  for (int nt = 0; nt < 2; ++nt) {
    const int qq = q0 + wq + nt * 16 + lo4;
    unsigned short* cb = ctxb + ((long)(b * 512 + qq)) * 512 + h * 64;
#pragma unroll
    for (int mt = 0; mt < 2; ++mt) {
      u16x4 o;
#pragma unroll
      for (int r = 0; r < 4; ++r) o[r] = f2b_rn(acc2[mt][nt][r]);
      *(u16x4*)&cb[wd + mt * 16 + hi4 * 4] = o;
    }
  }
}

// out = LayerNorm(a + b) * g + be ; fp32 + bf16, float4-vectorized, 128 threads.
__global__ __launch_bounds__(128)
void resid_ln(const float* __restrict__ a, const float* __restrict__ b,
              const float* __restrict__ g, const float* __restrict__ be,
              float* __restrict__ outf, unsigned short* __restrict__ outb) {
  const long row = blockIdx.x;
  const int t = threadIdx.x;
  const int wave = t >> 6, lane = t & 63;
  const f32x4 va = *(const f32x4*)&a[row * 512 + t * 4];
  const f32x4 vb = *(const f32x4*)&b[row * 512 + t * 4];
  f32x4 v;
  float s = 0.f, s2 = 0.f;
#pragma unroll
  for (int i = 0; i < 4; ++i) { v[i] = va[i] + vb[i]; s += v[i]; s2 += v[i] * v[i]; }
  for (int o = 32; o > 0; o >>= 1) { s += __shfl_down(s, o); s2 += __shfl_down(s2, o); }
  __shared__ float red[4];
  if (lane == 0) { red[wave] = s; red[2 + wave] = s2; }
  __syncthreads();
  s = red[0] + red[1];
  s2 = red[2] + red[3];
  const float mu  = s * (1.f / 512.f);
  const float var = s2 * (1.f / 512.f) - mu * mu;
  const float ri = rsqrtf(var + EPS_);
  const f32x4 vg = *(const f32x4*)&g[t * 4];
  const f32x4 ve = *(const f32x4*)&be[t * 4];
  f32x4 y;
  u16x4 yb;
#pragma unroll
  for (int i = 0; i < 4; ++i) { y[i] = (v[i] - mu) * ri * vg[i] + ve[i]; yb[i] = f2b_rn(y[i]); }
  *(f32x4*)&outf[row * 512 + t * 4] = y;
  *(u16x4*)&outb[row * 512 + t * 4] = yb;
}

__global__ void f2b_arr(const float* __restrict__ in, unsigned short* __restrict__ out, long n4) {
  long i = (long)blockIdx.x * 256 + threadIdx.x;
  const long stride = (long)gridDim.x * 256;
  for (; i < n4; i += stride) {
    const f32x4 v = *(const f32x4*)&in[i * 4];
    u16x4 o;
#pragma unroll
    for (int k = 0; k < 4; ++k) o[k] = f2b_rn(v[k]);
    *(u16x4*)&out[i * 4] = o;
  }
}

__global__ void copy_conv(const float* __restrict__ in, float* __restrict__ outf,
                          unsigned short* __restrict__ outb, long n4) {
  long i = (long)blockIdx.x * 256 + threadIdx.x;
  const long stride = (long)gridDim.x * 256;
  for (; i < n4; i += stride) {
    const f32x4 v = *(const f32x4*)&in[i * 4];
    u16x4 o;
#pragma unroll
    for (int k = 0; k < 4; ++k) o[k] = f2b_rn(v[k]);
    *(f32x4*)&outf[i * 4] = v;
    *(u16x4*)&outb[i * 4] = o;
  }
}

extern "C" void kernel_launch(void* const* d_in, const int* in_sizes, int n_in,
                              void* d_out, int out_size, void* d_ws, size_t ws_size,
                              hipStream_t stream) {
  const float* src  = (const float*)d_in[0];
  const float* Wqkv = (const float*)d_in[1];
  const float* bqkv = (const float*)d_in[2];
  const float* Wo   = (const float*)d_in[3];
  const float* bo   = (const float*)d_in[4];
  const float* W1   = (const float*)d_in[5];
  const float* b1   = (const float*)d_in[6];
  const float* W2   = (const float*)d_in[7];
  const float* b2   = (const float*)d_in[8];
  const float* g1   = (const float*)d_in[9];
  const float* be1  = (const float*)d_in[10];
  const float* g2   = (const float*)d_in[11];
  const float* be2  = (const float*)d_in[12];

  char* p = (char*)d_ws;
  auto take = [&](size_t bytes) { void* r = (void*)p; p += (bytes + 255) & ~(size_t)255; return r; };
  float* x        = (float*)take((size_t)BL * 512 * 4);
  float* x1       = (float*)take((size_t)BL * 512 * 4);
  float* attn_out = (float*)take((size_t)BL * 512 * 4);
  float* ff2      = (float*)take((size_t)BL * 512 * 4);
  unsigned short* xbf    = (unsigned short*)take((size_t)BL * 512 * 2);
  unsigned short* qkvbf  = (unsigned short*)take((size_t)BL * 1536 * 2);
  unsigned short* ctxbf  = (unsigned short*)take((size_t)BL * 512 * 2);
  unsigned short* ff1bf  = (unsigned short*)take((size_t)BL * 2048 * 2);
  unsigned short* Wqkvb  = (unsigned short*)take((size_t)4 * 1536 * 512 * 2);
  unsigned short* Wob    = (unsigned short*)take((size_t)4 * 512 * 512 * 2);
  unsigned short* W1b    = (unsigned short*)take((size_t)4 * 2048 * 512 * 2);
  unsigned short* W2b    = (unsigned short*)take((size_t)4 * 512 * 2048 * 2);

  f2b_arr<<<1024, 256, 0, stream>>>(Wqkv, Wqkvb, 4L * 1536 * 512 / 4);
  f2b_arr<<<512,  256, 0, stream>>>(Wo,   Wob,   4L * 512 * 512 / 4);
  f2b_arr<<<1024, 256, 0, stream>>>(W1,   W1b,   4L * 2048 * 512 / 4);
  f2b_arr<<<1024, 256, 0, stream>>>(W2,   W2b,   4L * 512 * 2048 / 4);
  copy_conv<<<1024, 256, 0, stream>>>(src, x, xbf, (long)BL * 512 / 4);

  float* out_x    = (float*)d_out;
  float* out_attn = out_x + (size_t)BL * 512;

  for (int i = 0; i < NL_; ++i) {
    // QKV: [4096,1536] = x @ Wqkv^T + bqkv  (bf16 out); 64x128 tiles -> 768 blocks
    gemm_bt<64, 128, 2, 4><<<dim3(BL / 64, 1536 / 128, 1), 256, 0, stream>>>(
        xbf, 512, 0, 0, Wqkvb + (size_t)i * 1536 * 512, 512, 0, 0,
        nullptr, qkvbf, 1536, 0, 0, bqkv + (size_t)i * 1536, 512, 1.f, 0, 1);

    // fused scores+softmax+PV: fp32 attn -> d_out, ctx bf16 -> ctxbf
    float* attnL = out_attn + (size_t)i * 64 * 512 * 512;
    attn_fused<<<dim3(8, 64), 256, 0, stream>>>(qkvbf, attnL, ctxbf);

    // attn_out = ctx @ Wo^T + bo  (fp32)
    gemm_bt<128, 64, 4, 2><<<dim3(32, 8, 1), 256, 0, stream>>>(
        ctxbf, 512, 0, 0, Wob + (size_t)i * 512 * 512, 512, 0, 0,
        attn_out, nullptr, 512, 0, 0, bo + (size_t)i * 512, 512, 1.f, 0, 1);

    // x1 = LN(x + attn_out)
    resid_ln<<<BL, 128, 0, stream>>>(x, attn_out, g1 + (size_t)i * 512, be1 + (size_t)i * 512, x1, xbf);

    // ff1 = relu(x1 @ W1^T + b1)  (bf16)
    gemm_bt<128, 128, 4, 4><<<dim3(32, 16, 1), 256, 0, stream>>>(
        xbf, 512, 0, 0, W1b + (size_t)i * 2048 * 512, 512, 0, 0,
        nullptr, ff1bf, 2048, 0, 0, b1 + (size_t)i * 2048, 512, 1.f, 1, 1);

    // ff2 = ff1 @ W2^T + b2  (fp32)
    gemm_bt<128, 64, 4, 2><<<dim3(32, 8, 1), 256, 0, stream>>>(
        ff1bf, 2048, 0, 0, W2b + (size_t)i * 512 * 2048, 2048, 0, 0,
        ff2, nullptr, 512, 0, 0, b2 + (size_t)i * 512, 2048, 1.f, 0, 1);

    // x = LN(x1 + ff2); final layer writes straight to d_out
    resid_ln<<<BL, 128, 0, stream>>>(x1, ff2, g2 + (size_t)i * 512, be2 + (size_t)i * 512,
                                     (i == 3) ? out_x : x, xbf);
  }
}